// Round 1
// baseline (880.596 us; speedup 1.0000x reference)
//
#include <hip/hip_runtime.h>

#define B_    64
#define C_    256
#define H_    56
#define W_    56
#define N_    6890
#define HW_   3136
#define NTILE 108   // ceil(6890/64)

typedef __attribute__((ext_vector_type(8))) __bf16 bf16x8;
typedef __attribute__((ext_vector_type(8))) unsigned short ushort8;
typedef __attribute__((ext_vector_type(4))) float f32x4;
typedef __attribute__((ext_vector_type(4))) unsigned int uint4v;
typedef __attribute__((ext_vector_type(2))) unsigned int uint2v;

__device__ __forceinline__ unsigned short f2bf(float f) {
    unsigned int u = __builtin_bit_cast(unsigned int, f);
    u += 0x7FFFu + ((u >> 16) & 1u);   // RTNE
    return (unsigned short)(u >> 16);
}
__device__ __forceinline__ unsigned int pack2(float lo, float hi) {
    return (unsigned int)f2bf(lo) | ((unsigned int)f2bf(hi) << 16);
}
__device__ __forceinline__ float leaky(float v) { return v > 0.f ? v : 0.01f * v; }

// A-fragment for mfma_f32_16x16x32_bf16: lane holds row (lane&15), k = k0 + 8*(lane>>4) + j
__device__ __forceinline__ bf16x8 afrag(const float* __restrict__ wp, int ldk,
                                        int rowbase, int k0, int lane, int nrows) {
    int i = rowbase + (lane & 15);
    int k = k0 + ((lane >> 4) << 3);
    ushort8 u;
    if (i < nrows) {
        const float* s = wp + (size_t)i * ldk + k;
#pragma unroll
        for (int j = 0; j < 8; j++) u[j] = f2bf(s[j]);
    } else {
#pragma unroll
        for (int j = 0; j < 8; j++) u[j] = 0;
    }
    return __builtin_bit_cast(bf16x8, u);
}

// B-fragment from swizzled LDS: buf[n][cd ^ ((n&7)<<2)], 8 bf16 (4 dwords) starting at k0
__device__ __forceinline__ bf16x8 bfrag(const unsigned int* buf, int rowstride_dw,
                                        int n, int k0) {
    int cd = (k0 >> 1) ^ ((n & 7) << 2);   // k0 multiple of 8 -> cd 4-aligned; XOR bits 2..4 keep block intact
    uint4v v = *(const uint4v*)(buf + n * rowstride_dw + cd);
    return __builtin_bit_cast(bf16x8, v);
}

__global__ __launch_bounds__(256) void maf_kernel(
    const float* __restrict__ points, const float* __restrict__ im,
    const float* __restrict__ w0, const float* __restrict__ b0,
    const float* __restrict__ w1, const float* __restrict__ b1,
    const float* __restrict__ w2, const float* __restrict__ b2,
    float* __restrict__ out0, float* __restrict__ out1)
{
    __shared__ unsigned int Xs[64 * 128];   // X  [n=64][c=256] bf16, 2ch/dword, swizzled  (32KB)
    __shared__ unsigned int Y0s[64 * 64];   // Y0 [n=64][m=128] bf16, swizzled             (16KB)
    __shared__ unsigned int Y1s[64 * 32];   // Y1 [n=64][m=64]  bf16, swizzled             (8KB)

    const int t    = threadIdx.x;
    const int lane = t & 63;
    const int wave = t >> 6;
    const int bid  = blockIdx.x;
    const int b    = bid / NTILE;
    const int tile = bid - b * NTILE;
    const int n0   = tile * 64;

    // ---- per-point bilinear params (this lane's point, kept for whole staging loop) ----
    const int gn  = n0 + lane;
    const bool pv = gn < N_;
    float px = -1.f, py = -1.f;
    if (pv) {
        const float* pp = points + ((size_t)b * N_ + gn) * 2;
        px = pp[0]; py = pp[1];
    }
    float fx = (px + 1.f) * 0.5f * (W_ - 1);
    float fy = (py + 1.f) * 0.5f * (H_ - 1);
    float x0f = floorf(fx), y0f = floorf(fy);
    int x0 = (int)x0f, y0 = (int)y0f;
    int x1 = x0 + 1, y1 = y0 + 1;
    float wx1 = fx - x0f, wy1 = fy - y0f;
    float wx0 = 1.f - wx1, wy0 = 1.f - wy1;
    bool vx0 = (x0 >= 0) & (x0 < W_), vx1 = (x1 >= 0) & (x1 < W_);
    bool vy0 = (y0 >= 0) & (y0 < H_), vy1 = (y1 >= 0) & (y1 < H_);
    int xc0 = min(max(x0, 0), W_ - 1), xc1 = min(max(x1, 0), W_ - 1);
    int yc0 = min(max(y0, 0), H_ - 1), yc1 = min(max(y1, 0), H_ - 1);
    float w00 = (pv && vy0 && vx0) ? wy0 * wx0 : 0.f;
    float w01 = (pv && vy0 && vx1) ? wy0 * wx1 : 0.f;
    float w10 = (pv && vy1 && vx0) ? wy1 * wx0 : 0.f;
    float w11 = (pv && vy1 && vx1) ? wy1 * wx1 : 0.f;
    int o00 = yc0 * W_ + xc0, o01 = yc0 * W_ + xc1;
    int o10 = yc1 * W_ + xc0, o11 = yc1 * W_ + xc1;

    const float* imb = im + (size_t)b * C_ * HW_;
    float* pfb = out1 + (size_t)b * C_ * N_ + n0;
    const int swz = (lane & 7) << 2;

    // ---- stage: bilinear-sample 2 channels per thread per iter ----
#pragma unroll 4
    for (int i = 0; i < 32; i++) {
        int p  = wave * 32 + i;        // channel pair index 0..127
        int c0 = p * 2;
        const float* s0 = imb + (size_t)c0 * HW_;
        const float* s1 = s0 + HW_;
        float v0 = w00 * s0[o00] + w01 * s0[o01] + w10 * s0[o10] + w11 * s0[o11];
        float v1 = w00 * s1[o00] + w01 * s1[o01] + w10 * s1[o10] + w11 * s1[o11];
        if (pv) {
            pfb[(size_t)c0 * N_ + lane]       = v0;   // coalesced over lane
            pfb[(size_t)(c0 + 1) * N_ + lane] = v1;
        }
        Xs[lane * 128 + (p ^ swz)] = pack2(v0, v1);
    }

    // ---- layer 1 A preload: wave handles output rows [wave*32, wave*32+32) ----
    bf16x8 a1[2][8];
#pragma unroll
    for (int mt = 0; mt < 2; mt++)
#pragma unroll
        for (int ks = 0; ks < 8; ks++)
            a1[mt][ks] = afrag(w0, 256, (wave * 2 + mt) * 16, ks * 32, lane, 1 << 30);

    __syncthreads();

    const int cl = lane & 15;
    const int rh = lane >> 4;
    const int kq = rh << 3;

    // ---- layer 1: Y0[128,64] = leaky(W0[128,256] @ X[256,64] + b0) ----
    f32x4 acc1[2][4] = {};
#pragma unroll
    for (int ks = 0; ks < 8; ks++) {
        bf16x8 bx[4];
#pragma unroll
        for (int nt = 0; nt < 4; nt++)
            bx[nt] = bfrag(Xs, 128, nt * 16 + cl, ks * 32 + kq);
#pragma unroll
        for (int mt = 0; mt < 2; mt++)
#pragma unroll
            for (int nt = 0; nt < 4; nt++)
                acc1[mt][nt] = __builtin_amdgcn_mfma_f32_16x16x32_bf16(
                    a1[mt][ks], bx[nt], acc1[mt][nt], 0, 0, 0);
    }

    // epilogue 1 -> Y0s (bias + leaky + bf16 pack)
#pragma unroll
    for (int mt = 0; mt < 2; mt++) {
        int m0 = (wave * 2 + mt) * 16 + (rh << 2);
        f32x4 bias = *(const f32x4*)(b0 + m0);
#pragma unroll
        for (int nt = 0; nt < 4; nt++) {
            int nn = nt * 16 + cl;
            float v0 = leaky(acc1[mt][nt][0] + bias[0]);
            float v1 = leaky(acc1[mt][nt][1] + bias[1]);
            float v2 = leaky(acc1[mt][nt][2] + bias[2]);
            float v3 = leaky(acc1[mt][nt][3] + bias[3]);
            int md = (m0 >> 1) ^ ((nn & 7) << 2);
            uint2v pk; pk[0] = pack2(v0, v1); pk[1] = pack2(v2, v3);
            *(uint2v*)(Y0s + nn * 64 + md) = pk;
        }
    }

    // layer 2 A preload: wave handles output rows [wave*16, wave*16+16); K = 384 = [Y0(128) | X(256)]
    bf16x8 a2[12];
#pragma unroll
    for (int ks = 0; ks < 12; ks++)
        a2[ks] = afrag(w1, 384, wave * 16, ks * 32, lane, 1 << 30);

    __syncthreads();

    f32x4 acc2[4] = {};
#pragma unroll
    for (int ks = 0; ks < 12; ks++) {
#pragma unroll
        for (int nt = 0; nt < 4; nt++) {
            bf16x8 bx = (ks < 4) ? bfrag(Y0s, 64, nt * 16 + cl, ks * 32 + kq)
                                 : bfrag(Xs, 128, nt * 16 + cl, (ks - 4) * 32 + kq);
            acc2[nt] = __builtin_amdgcn_mfma_f32_16x16x32_bf16(a2[ks], bx, acc2[nt], 0, 0, 0);
        }
    }

    // epilogue 2 -> Y1s
    {
        int m0 = wave * 16 + (rh << 2);
        f32x4 bias = *(const f32x4*)(b1 + m0);
#pragma unroll
        for (int nt = 0; nt < 4; nt++) {
            int nn = nt * 16 + cl;
            float v0 = leaky(acc2[nt][0] + bias[0]);
            float v1 = leaky(acc2[nt][1] + bias[1]);
            float v2 = leaky(acc2[nt][2] + bias[2]);
            float v3 = leaky(acc2[nt][3] + bias[3]);
            int md = (m0 >> 1) ^ ((nn & 7) << 2);
            uint2v pk; pk[0] = pack2(v0, v1); pk[1] = pack2(v2, v3);
            *(uint2v*)(Y1s + nn * 32 + md) = pk;
        }
    }

    // layer 3 A preload: W2 padded to 16 rows; K = 320 = [Y1(64) | X(256)]
    bf16x8 a3[10];
#pragma unroll
    for (int ks = 0; ks < 10; ks++)
        a3[ks] = afrag(w2, 320, 0, ks * 32, lane, 5);

    __syncthreads();

    // ---- layer 3: each wave owns one 16-col N-tile (nt = wave) ----
    {
        int nn = wave * 16 + cl;
        f32x4 acc3 = {};
#pragma unroll
        for (int ks = 0; ks < 10; ks++) {
            bf16x8 bx = (ks < 2) ? bfrag(Y1s, 32, nn, ks * 32 + kq)
                                 : bfrag(Xs, 128, nn, (ks - 2) * 32 + kq);
            acc3 = __builtin_amdgcn_mfma_f32_16x16x32_bf16(a3[ks], bx, acc3, 0, 0, 0);
        }
        int gn2 = n0 + nn;
        if (gn2 < N_) {
#pragma unroll
            for (int r = 0; r < 4; r++) {
                int m = (rh << 2) + r;
                if (m < 5) {
                    float v = acc3[r] + b2[m];
                    v = v > 0.f ? v : 0.f;   // final relu
                    out0[((size_t)b * 5 + m) * N_ + gn2] = v;
                }
            }
        }
    }
}

extern "C" void kernel_launch(void* const* d_in, const int* in_sizes, int n_in,
                              void* d_out, int out_size, void* d_ws, size_t ws_size,
                              hipStream_t stream) {
    const float* points = (const float*)d_in[0];
    const float* im     = (const float*)d_in[1];
    const float* w0     = (const float*)d_in[2];
    const float* b0     = (const float*)d_in[3];
    const float* w1     = (const float*)d_in[4];
    const float* b1     = (const float*)d_in[5];
    const float* w2     = (const float*)d_in[6];
    const float* b2     = (const float*)d_in[7];
    float* out0 = (float*)d_out;                        // mesh_align_feat [64][5*6890]
    float* out1 = out0 + (size_t)B_ * 5 * N_;           // point_feat      [64][256][6890]

    dim3 grid(B_ * NTILE), block(256);
    hipLaunchKernelGGL(maf_kernel, grid, block, 0, stream,
                       points, im, w0, b0, w1, b1, w2, b2, out0, out1);
}

// Round 2
// 375.842 us; speedup vs baseline: 2.3430x; 2.3430x over previous
//
#include <hip/hip_runtime.h>

#define B_    64
#define C_    256
#define H_    56
#define W_    56
#define N_    6890
#define HW_   3136
#define NTILE 108          // ceil(6890/64) MLP point tiles
#define GPTS  1723         // ceil(6890/4)  gather points per block
#define PPT   7            // ceil(1723/256) points per thread

#define WB1_OFF (128*256)
#define WB2_OFF (128*256 + 64*384)
#define WTOT    (128*256 + 64*384 + 5*320)   // 58944 bf16 weight elements

typedef __attribute__((ext_vector_type(8))) __bf16 bf16x8;
typedef __attribute__((ext_vector_type(8))) unsigned short ushort8;
typedef __attribute__((ext_vector_type(4))) float f32x4;
typedef __attribute__((ext_vector_type(2))) float f32x2;
typedef __attribute__((ext_vector_type(4))) unsigned int uint4v;
typedef __attribute__((ext_vector_type(2))) unsigned int uint2v;

__device__ __forceinline__ unsigned short f2bf(float f) {
    unsigned int u = __builtin_bit_cast(unsigned int, f);
    u += 0x7FFFu + ((u >> 16) & 1u);   // RTNE
    return (unsigned short)(u >> 16);
}
__device__ __forceinline__ unsigned int pack2(float lo, float hi) {
    return (unsigned int)f2bf(lo) | ((unsigned int)f2bf(hi) << 16);
}
__device__ __forceinline__ float leaky(float v) { return v > 0.f ? v : 0.01f * v; }

// ============================ kernel 0: weight bf16 pack ============================
__global__ void wconv_kernel(const float* __restrict__ w0, const float* __restrict__ w1,
                             const float* __restrict__ w2, unsigned short* __restrict__ wb) {
    int i = blockIdx.x * 256 + threadIdx.x;
    if (i >= WTOT) return;
    float v = (i < WB1_OFF) ? w0[i] : (i < WB2_OFF) ? w1[i - WB1_OFF] : w2[i - WB2_OFF];
    wb[i] = f2bf(v);
}

// ============================ kernel 1: bilinear gather =============================
// grid = 256 blocks: XCD-swizzled (batch, quarter). Each block: all 256 channels in
// 64 chunks of 4 planes; planes staged to LDS (reg double-buffer), points gathered
// from LDS, fp32 point_feat written coalesced.
__device__ __forceinline__ void stage_load(f32x4* rs, const float* src, int t) {
#pragma unroll
    for (int k = 0; k < 13; k++) {
        int idx = t + (k << 8);
        f32x4 z = {0.f, 0.f, 0.f, 0.f};
        rs[k] = (idx < 3136) ? ((const f32x4*)src)[idx] : z;   // 4 planes = 50176B flat
    }
}
__device__ __forceinline__ void stage_write(float* dst, const f32x4* rs, int t) {
#pragma unroll
    for (int k = 0; k < 13; k++) {
        int idx = t + (k << 8);
        if (idx < 3136) ((f32x4*)dst)[idx] = rs[k];
    }
}

__global__ __launch_bounds__(256) void gather_kernel(
    const float* __restrict__ points, const float* __restrict__ im,
    float* __restrict__ out1) {
    __shared__ float Ls[2][4 * HW_];     // 2 x 4 planes, 100352 B

    const int t   = threadIdx.x;
    const int bid = blockIdx.x;
    // bijective swizzle: batch b's 4 quarter-blocks land on the same XCD (bid%8)
    const int xcd  = bid & 7;
    const int slot = bid >> 3;              // 0..31
    const int b    = (slot >> 2) * 8 + xcd; // 0..63
    const int grp  = slot & 3;              // 0..3
    const int nbase = grp * GPTS;

    // ---- per-point bilinear params, computed ONCE per block ----
    int   ia0[PPT], ia1[PPT];
    float wl0[PPT], wr0[PPT], wl1[PPT], wr1[PPT];
#pragma unroll
    for (int p = 0; p < PPT; p++) {
        int ln = t + (p << 8);
        int n  = nbase + ln;
        bool ok = (ln < GPTS) && (n < N_);
        int nl = ok ? n : 0;
        f32x2 pt = *(const f32x2*)(points + ((size_t)b * N_ + nl) * 2);
        float fx = fminf(fmaxf((pt.x + 1.f) * 27.5f, 0.f), 55.f);
        float fy = fminf(fmaxf((pt.y + 1.f) * 27.5f, 0.f), 55.f);
        float x0f = floorf(fx), y0f = floorf(fy);
        int x0 = (int)x0f, y0 = (int)y0f;
        float wx1 = fx - x0f, wy1 = fy - y0f;
        float wx0 = 1.f - wx1, wy0 = 1.f - wy1;
        bool hix = x0 >= W_ - 1;           // fx==55 edge: wx1==0, value lives at col 55
        int   xb  = hix ? W_ - 2 : x0;
        float wxl = hix ? 0.f : wx0;
        float wxr = hix ? wx0 : wx1;
        int y0c = min(y0, H_ - 1);
        int y1c = min(y0 + 1, H_ - 1);     // y==55 edge: wy1==0, clamped row harmless
        float g = ok ? 1.f : 0.f;
        wl0[p] = wy0 * wxl * g; wr0[p] = wy0 * wxr * g;
        wl1[p] = wy1 * wxl * g; wr1[p] = wy1 * wxr * g;
        ia0[p] = y0c * W_ + xb; ia1[p] = y1c * W_ + xb;
    }

    const float* imb = im + (size_t)b * C_ * HW_;
    f32x4 rs[13];

    stage_load(rs, imb, t);
    stage_write(Ls[0], rs, t);
    __syncthreads();

    for (int ch = 0; ch < 64; ch++) {
        const int buf = ch & 1;
        if (ch < 63) stage_load(rs, imb + (size_t)(ch + 1) * 4 * HW_, t);

        const int c0 = ch * 4;
        const float* plane = Ls[buf];
#pragma unroll
        for (int p = 0; p < PPT; p++) {
            int ln = t + (p << 8);
            int n  = nbase + ln;
            bool ok = (ln < GPTS) && (n < N_);
            size_t obase = ((size_t)b * C_ + c0) * N_ + n;
#pragma unroll
            for (int j = 0; j < 4; j++) {
                const float* q = plane + j * HW_;
                float v = wl0[p] * q[ia0[p]] + wr0[p] * q[ia0[p] + 1]
                        + wl1[p] * q[ia1[p]] + wr1[p] * q[ia1[p] + 1];
                if (ok) out1[obase + (size_t)j * N_] = v;
            }
        }
        if (ch < 63) stage_write(Ls[buf ^ 1], rs, t);
        __syncthreads();
    }
}

// ============================ kernel 2: MFMA MLP ====================================
__device__ __forceinline__ bf16x8 afrag_f32(const float* __restrict__ wp, int ldk,
                                            int rowbase, int k0, int lane, int nrows) {
    int i = rowbase + (lane & 15);
    int k = k0 + ((lane >> 4) << 3);
    ushort8 u;
    if (i < nrows) {
        const float* s = wp + (size_t)i * ldk + k;
#pragma unroll
        for (int j = 0; j < 8; j++) u[j] = f2bf(s[j]);
    } else {
#pragma unroll
        for (int j = 0; j < 8; j++) u[j] = 0;
    }
    return __builtin_bit_cast(bf16x8, u);
}
__device__ __forceinline__ bf16x8 afrag_bf(const unsigned short* __restrict__ wb, int ldk,
                                           int rowbase, int k0, int lane, int nrows) {
    int i = rowbase + (lane & 15);
    int k = k0 + ((lane >> 4) << 3);
    if (i < nrows) return __builtin_bit_cast(bf16x8, *(const ushort8*)(wb + (size_t)i * ldk + k));
    ushort8 z = {0, 0, 0, 0, 0, 0, 0, 0};
    return __builtin_bit_cast(bf16x8, z);
}

// B-fragment from swizzled LDS: buf[n][cd ^ ((n&7)<<2)], 4 dwords at k0
__device__ __forceinline__ bf16x8 bfrag(const unsigned int* buf, int rowstride_dw,
                                        int n, int k0) {
    int cd = (k0 >> 1) ^ ((n & 7) << 2);
    uint4v v = *(const uint4v*)(buf + n * rowstride_dw + cd);
    return __builtin_bit_cast(bf16x8, v);
}

template <bool BF16W>
__global__ __launch_bounds__(256) void mlp_kernel(
    const float* __restrict__ pf,        // point_feat (= out1), read back
    const float* __restrict__ w0, const float* __restrict__ b0,
    const float* __restrict__ w1, const float* __restrict__ b1,
    const float* __restrict__ w2, const float* __restrict__ b2,
    const unsigned short* __restrict__ wb,
    float* __restrict__ out0) {
    __shared__ unsigned int Xs[64 * 128];   // X  [n=64][c=256] bf16, swizzled (32KB)
    __shared__ unsigned int Y0s[64 * 64];   // Y0 [n][m=128] bf16 (16KB); Y1 aliased in

    const int t    = threadIdx.x;
    const int lane = t & 63;
    const int wave = t >> 6;
    const int bid  = blockIdx.x;
    const int b    = bid / NTILE;
    const int tile = bid - b * NTILE;
    const int n0   = tile * 64;

    // ---- stage X tile from point_feat (coalesced scalar-per-lane) ----
    const float* pfb = pf + (size_t)b * C_ * N_;
    const int nn_g = min(n0 + lane, N_ - 1);
    const int swz  = (lane & 7) << 2;
#pragma unroll
    for (int g8 = 0; g8 < 8; g8++) {
        int c0 = wave * 64 + g8 * 8;
        float v[8];
#pragma unroll
        for (int j = 0; j < 8; j++) v[j] = pfb[(size_t)(c0 + j) * N_ + nn_g];
        uint4v pk;
        pk[0] = pack2(v[0], v[1]); pk[1] = pack2(v[2], v[3]);
        pk[2] = pack2(v[4], v[5]); pk[3] = pack2(v[6], v[7]);
        *(uint4v*)(Xs + lane * 128 + ((c0 >> 1) ^ swz)) = pk;
    }

    // ---- layer 1 A preload ----
    bf16x8 a1[2][8];
#pragma unroll
    for (int mt = 0; mt < 2; mt++)
#pragma unroll
        for (int ks = 0; ks < 8; ks++)
            a1[mt][ks] = BF16W ? afrag_bf(wb, 256, (wave * 2 + mt) * 16, ks * 32, lane, 1 << 30)
                               : afrag_f32(w0, 256, (wave * 2 + mt) * 16, ks * 32, lane, 1 << 30);

    __syncthreads();

    const int cl = lane & 15;
    const int rh = lane >> 4;
    const int kq = rh << 3;

    // ---- layer 1: Y0[128,64] = leaky(W0 @ X + b0) ----
    f32x4 acc1[2][4] = {};
#pragma unroll
    for (int ks = 0; ks < 8; ks++) {
        bf16x8 bx[4];
#pragma unroll
        for (int nt = 0; nt < 4; nt++)
            bx[nt] = bfrag(Xs, 128, nt * 16 + cl, ks * 32 + kq);
#pragma unroll
        for (int mt = 0; mt < 2; mt++)
#pragma unroll
            for (int nt = 0; nt < 4; nt++)
                acc1[mt][nt] = __builtin_amdgcn_mfma_f32_16x16x32_bf16(
                    a1[mt][ks], bx[nt], acc1[mt][nt], 0, 0, 0);
    }

#pragma unroll
    for (int mt = 0; mt < 2; mt++) {
        int m0 = (wave * 2 + mt) * 16 + (rh << 2);
        f32x4 bias = *(const f32x4*)(b0 + m0);
#pragma unroll
        for (int nt = 0; nt < 4; nt++) {
            int nn = nt * 16 + cl;
            float v0 = leaky(acc1[mt][nt][0] + bias[0]);
            float v1 = leaky(acc1[mt][nt][1] + bias[1]);
            float v2 = leaky(acc1[mt][nt][2] + bias[2]);
            float v3 = leaky(acc1[mt][nt][3] + bias[3]);
            int md = (m0 >> 1) ^ ((nn & 7) << 2);
            uint2v pk; pk[0] = pack2(v0, v1); pk[1] = pack2(v2, v3);
            *(uint2v*)(Y0s + nn * 64 + md) = pk;
        }
    }

    // ---- layer 2 A preload: K = 384 = [Y0(128) | X(256)] ----
    bf16x8 a2[12];
#pragma unroll
    for (int ks = 0; ks < 12; ks++)
        a2[ks] = BF16W ? afrag_bf(wb + WB1_OFF, 384, wave * 16, ks * 32, lane, 1 << 30)
                       : afrag_f32(w1, 384, wave * 16, ks * 32, lane, 1 << 30);

    __syncthreads();

    f32x4 acc2[4] = {};
#pragma unroll
    for (int ks = 0; ks < 12; ks++) {
#pragma unroll
        for (int nt = 0; nt < 4; nt++) {
            bf16x8 bx = (ks < 4) ? bfrag(Y0s, 64, nt * 16 + cl, ks * 32 + kq)
                                 : bfrag(Xs, 128, nt * 16 + cl, (ks - 4) * 32 + kq);
            acc2[nt] = __builtin_amdgcn_mfma_f32_16x16x32_bf16(a2[ks], bx, acc2[nt], 0, 0, 0);
        }
    }

    // layer 3 A preload (W2 zero-padded to 16 rows); K = 320 = [Y1(64) | X(256)]
    bf16x8 a3[10];
#pragma unroll
    for (int ks = 0; ks < 10; ks++)
        a3[ks] = BF16W ? afrag_bf(wb + WB2_OFF, 320, 0, ks * 32, lane, 5)
                       : afrag_f32(w2, 320, 0, ks * 32, lane, 5);

    __syncthreads();   // all waves done READING Y0s before Y1 overwrites it

    // ---- epilogue 2 -> Y1s (aliases Y0s) ----
    {
        int m0 = wave * 16 + (rh << 2);
        f32x4 bias = *(const f32x4*)(b1 + m0);
#pragma unroll
        for (int nt = 0; nt < 4; nt++) {
            int nn = nt * 16 + cl;
            float v0 = leaky(acc2[nt][0] + bias[0]);
            float v1 = leaky(acc2[nt][1] + bias[1]);
            float v2 = leaky(acc2[nt][2] + bias[2]);
            float v3 = leaky(acc2[nt][3] + bias[3]);
            int md = (m0 >> 1) ^ ((nn & 7) << 2);
            uint2v pk; pk[0] = pack2(v0, v1); pk[1] = pack2(v2, v3);
            *(uint2v*)(Y0s + nn * 32 + md) = pk;   // Y1 layout: [n][32 dwords]
        }
    }

    __syncthreads();

    // ---- layer 3: each wave owns one 16-col N-tile ----
    {
        int nn = wave * 16 + cl;
        f32x4 acc3 = {};
#pragma unroll
        for (int ks = 0; ks < 10; ks++) {
            bf16x8 bx = (ks < 2) ? bfrag(Y0s, 32, nn, ks * 32 + kq)
                                 : bfrag(Xs, 128, nn, (ks - 2) * 32 + kq);
            acc3 = __builtin_amdgcn_mfma_f32_16x16x32_bf16(a3[ks], bx, acc3, 0, 0, 0);
        }
        int gn2 = n0 + nn;
        if (gn2 < N_) {
#pragma unroll
            for (int r = 0; r < 4; r++) {
                int m = (rh << 2) + r;
                if (m < 5) {
                    float v = acc3[r] + b2[m];
                    v = v > 0.f ? v : 0.f;   // final relu
                    out0[((size_t)b * 5 + m) * N_ + gn2] = v;
                }
            }
        }
    }
}

extern "C" void kernel_launch(void* const* d_in, const int* in_sizes, int n_in,
                              void* d_out, int out_size, void* d_ws, size_t ws_size,
                              hipStream_t stream) {
    const float* points = (const float*)d_in[0];
    const float* im     = (const float*)d_in[1];
    const float* w0     = (const float*)d_in[2];
    const float* b0     = (const float*)d_in[3];
    const float* w1     = (const float*)d_in[4];
    const float* b1     = (const float*)d_in[5];
    const float* w2     = (const float*)d_in[6];
    const float* b2     = (const float*)d_in[7];
    float* out0 = (float*)d_out;                   // mesh_align_feat [64][5*6890]
    float* out1 = out0 + (size_t)B_ * 5 * N_;      // point_feat      [64][256][6890]

    const bool use_bf16w = (ws_size >= (size_t)WTOT * 2) && (d_ws != nullptr);
    unsigned short* wb = (unsigned short*)d_ws;

    if (use_bf16w) {
        hipLaunchKernelGGL(wconv_kernel, dim3((WTOT + 255) / 256), dim3(256), 0, stream,
                           w0, w1, w2, wb);
    }
    hipLaunchKernelGGL(gather_kernel, dim3(256), dim3(256), 0, stream,
                       points, im, out1);
    if (use_bf16w) {
        hipLaunchKernelGGL(mlp_kernel<true>, dim3(B_ * NTILE), dim3(256), 0, stream,
                           out1, w0, b0, w1, b1, w2, b2, wb, out0);
    } else {
        hipLaunchKernelGGL(mlp_kernel<false>, dim3(B_ * NTILE), dim3(256), 0, stream,
                           out1, w0, b0, w1, b1, w2, b2, (const unsigned short*)nullptr, out0);
    }
}